// Round 7
// baseline (405.627 us; speedup 1.0000x reference)
//
#include <hip/hip_runtime.h>
#include <stdint.h>

// BilinearScorer: out[n,r] = sum_{h,k} pred[n,h] U[h,r,k] args[n,k] + bias1[r,:].args[n,:] + bias2[r]
// n=4096, h=k=512, R=64.  137.4 GFLOP fp32-equivalent.
// R7 = R5 config (BM/BN/BK=128/128/64, grid r-slowest, verified XOR swizzle) with
// MFMA shape 32x32x16: frag regs halve (2+2 frags/phase) -> ~115-reg footprint fits
// launch_bounds(256,4) -> 4 blocks/CU (R5: 2.6) to cover barrier drains; 32x32 pipe
// is also ~20% faster (m119: 2495 TF vs 2075).  fp16 single-pass numerics (absmax 0.25).

#define HID   512
#define ROLES 64
#define NTOK  4096
#define BM    128
#define BN    128
#define BK    64

typedef __attribute__((ext_vector_type(8)))  _Float16 f16x8;   // MFMA A/B operand: 4 VGPRs
typedef __attribute__((ext_vector_type(4)))  _Float16 f16x4;
typedef __attribute__((ext_vector_type(16))) float    f32x16;  // 32x32 C/D: 16 f32/lane

__device__ __forceinline__ void async16(const void* g, void* l) {
  // global -> LDS direct copy, 16B/lane. LDS dest is wave-uniform base + lane*16;
  // per-lane SOURCE address is free (implements the store-side swizzle).
  __builtin_amdgcn_global_load_lds(
      (const __attribute__((address_space(1))) uint32_t*)g,
      (__attribute__((address_space(3))) uint32_t*)l, 16, 0, 0);
}

// ---- prep: pred fp32 -> fp16, fused out[n,r] = bias2[r] init ---------------
__global__ __launch_bounds__(256) void cvt_pred(const float* __restrict__ in,
                                                _Float16* __restrict__ outp,
                                                float* __restrict__ o,
                                                const float* __restrict__ b2) {
  const int idx = blockIdx.x * 256 + threadIdx.x;        // NTOK*HID/4 = 524288 threads
  const float4 v = ((const float4*)in)[idx];
  f16x4 t;
  t[0] = (_Float16)v.x; t[1] = (_Float16)v.y;
  t[2] = (_Float16)v.z; t[3] = (_Float16)v.w;
  ((f16x4*)outp)[idx] = t;
  if (idx < NTOK * ROLES) o[idx] = b2[idx & (ROLES - 1)];  // 262144 < 524288
}

// ---- prep: U[h][r][k] -> Ut[r][k][h] fp16, 128x128 fp32 LDS tile ----------
__global__ __launch_bounds__(256) void cvt_u(const float* __restrict__ U,
                                             _Float16* __restrict__ ut) {
  __shared__ float tile[128][129];               // stride 129 words: col reads conflict-free
  const int h0 = blockIdx.x * 128, k0 = blockIdx.y * 128, r = blockIdx.z;
  const int t = threadIdx.x;
  // read: 16 passes x 8 rows; 512B contiguous per row
  const int rr = t >> 5, c4 = (t & 31) * 4;
#pragma unroll
  for (int pass = 0; pass < 16; pass++) {
    const int row = pass * 8 + rr;
    const float4 v = *(const float4*)(U + ((size_t)(h0 + row) * ROLES + r) * HID + k0 + c4);
    tile[row][c4 + 0] = v.x; tile[row][c4 + 1] = v.y;
    tile[row][c4 + 2] = v.z; tile[row][c4 + 3] = v.w;
  }
  __syncthreads();
  // write: 8 passes x 16 k-rows; 256B contiguous per k-row
  const int kr = t >> 4, hc = (t & 15) * 8;
#pragma unroll
  for (int pass = 0; pass < 8; pass++) {
    const int k = pass * 16 + kr;
    alignas(16) _Float16 hb[8];
#pragma unroll
    for (int j = 0; j < 8; j++) hb[j] = (_Float16)tile[hc + j][k];
    *(uint4*)(ut + ((size_t)r * HID + k0 + k) * HID + h0 + hc) = *(const uint4*)hb;
  }
}

// ---- main fused GEMM ------------------------------------------------------
__global__ __launch_bounds__(256, 4) void bilinear_mfma(
    const _Float16* __restrict__ predf, const _Float16* __restrict__ utf,
    const float* __restrict__ args, const float* __restrict__ bias1,
    float* __restrict__ out) {
  __shared__ _Float16 sA[BM * BK];               // 16 KB
  __shared__ _Float16 sB[BN * BK];               // 16 KB

  const int nblk = blockIdx.x, mblk = blockIdx.y, r = blockIdx.z;
  const int m0 = mblk * BM, n0 = nblk * BN;
  const int tid  = threadIdx.x;
  const int wave = tid >> 6, lane = tid & 63;
  const int cn = lane & 31, half = lane >> 5, l7 = lane & 7;
  const int wm = (wave & 1) * 64, wn = (wave >> 1) * 64;  // wave-tile 64x64 = 2x2 of 32x32

  // staging: tile = 128 rows x 64 f16 (128B/row) = 1024 x 16B chunks, 4 calls each.
  // XOR swizzle: LDS slot s of row i holds global chunk (s ^ (i&7)) (R2-R6: 0 conflicts).
  const int i_loc = tid >> 3;                    // row 0..31 within call (+32/call)
  const int ko    = ((tid & 7) ^ (i_loc & 7)) * 8;
  const size_t offA = (size_t)(m0 + i_loc) * HID + ko;
  const size_t offB = ((size_t)r * HID + n0 + i_loc) * HID + ko;
  const int ldsW = wave * 512;                   // f16 elems (64 chunks/wave/call)

  // frag rows: 32x32x16 A/B operand: m(or n) = lane&31, k = (lane>>5)*8 + j.
  // row&7 == lane&7 for all frag rows (wm, 32*mt ≡ 0 mod 8).
  int rowA[2], rowB[2];
#pragma unroll
  for (int mt = 0; mt < 2; mt++) rowA[mt] = (wm + mt * 32 + cn) * BK;
#pragma unroll
  for (int nt = 0; nt < 2; nt++) rowB[nt] = (wn + nt * 32 + cn) * BK;

  f32x16 acc[2][2];
#pragma unroll
  for (int a = 0; a < 2; a++)
#pragma unroll
    for (int b = 0; b < 2; b++)
#pragma unroll
      for (int q = 0; q < 16; q++) acc[a][b][q] = 0.f;

  for (int k0 = 0; k0 < HID; k0 += BK) {
#pragma unroll
    for (int c = 0; c < 4; c++) {
      async16(predf + offA + (size_t)(c * 32) * HID + k0, sA + c * 2048 + ldsW);
      async16(utf   + offB + (size_t)(c * 32) * HID + k0, sB + c * 2048 + ldsW);
    }
    __syncthreads();                             // drains vmcnt (staging done)

#pragma unroll
    for (int ph = 0; ph < 4; ph++) {             // k-phase: k in [k0+16*ph, k0+16*ph+16)
      const int slot = (((ph << 1) | half) ^ l7) << 3;   // global chunk ph*2+half, swizzled
      const f16x8 a0 = *(const f16x8*)(sA + rowA[0] + slot);
      const f16x8 a1 = *(const f16x8*)(sA + rowA[1] + slot);
      const f16x8 b0 = *(const f16x8*)(sB + rowB[0] + slot);
      const f16x8 b1 = *(const f16x8*)(sB + rowB[1] + slot);
      acc[0][0] = __builtin_amdgcn_mfma_f32_32x32x16_f16(a0, b0, acc[0][0], 0, 0, 0);
      acc[0][1] = __builtin_amdgcn_mfma_f32_32x32x16_f16(a0, b1, acc[0][1], 0, 0, 0);
      acc[1][0] = __builtin_amdgcn_mfma_f32_32x32x16_f16(a1, b0, acc[1][0], 0, 0, 0);
      acc[1][1] = __builtin_amdgcn_mfma_f32_32x32x16_f16(a1, b1, acc[1][1], 0, 0, 0);
    }
    __syncthreads();
  }

  // epilogue: partial[m] = sum_n (T[m,n] + bias1[r,n]) * args[m,n], atomic into out.
  // 32x32 C/D layout (m74/m101): col = lane&31, row = 4*(lane>>5) + (reg&3) + 8*(reg>>2).
  float b1v[2];
#pragma unroll
  for (int nt = 0; nt < 2; nt++)
    b1v[nt] = bias1[r * HID + n0 + wn + nt * 32 + cn];

#pragma unroll
  for (int mt = 0; mt < 2; mt++) {
#pragma unroll
    for (int reg = 0; reg < 16; reg++) {
      const int row_m = half * 4 + (reg & 3) + ((reg >> 2) << 3);
      const int m = m0 + wm + mt * 32 + row_m;
      const float* arow = args + (size_t)m * HID + n0 + wn + cn;
      float s = (acc[mt][0][reg] + b1v[0]) * arow[0]
              + (acc[mt][1][reg] + b1v[1]) * arow[32];
      s += __shfl_xor(s, 1);
      s += __shfl_xor(s, 2);
      s += __shfl_xor(s, 4);
      s += __shfl_xor(s, 8);
      s += __shfl_xor(s, 16);                    // reduce over 32 n-columns
      if (cn == 0) atomicAdd(out + (size_t)m * ROLES + r, s);
    }
  }
}

// ---- correctness fallback if workspace is too small (slow, pure fp32) -----
__global__ __launch_bounds__(256) void fallback_k(
    const float* __restrict__ pred, const float* __restrict__ args,
    const float* __restrict__ U, const float* __restrict__ b1,
    const float* __restrict__ b2, float* __restrict__ out) {
  const int idx = blockIdx.x * 256 + threadIdx.x;   // 262144
  const int r = idx >> 12;                          // block-uniform role
  const int n = idx & (NTOK - 1);
  const float* arow = args + (size_t)n * HID;
  const float* prow = pred + (size_t)n * HID;
  float acc = 0.f;
  for (int h = 0; h < HID; h++) {
    const float* urow = U + ((size_t)h * ROLES + r) * HID;
    float s = 0.f;
    for (int k = 0; k < HID; k++) s = fmaf(urow[k], arow[k], s);
    acc = fmaf(prow[h], s, acc);
  }
  float sb = 0.f;
  const float* brow = b1 + (size_t)r * HID;
  for (int k = 0; k < HID; k++) sb = fmaf(brow[k], arow[k], sb);
  out[(size_t)n * ROLES + r] = acc + sb + b2[r];
}

extern "C" void kernel_launch(void* const* d_in, const int* in_sizes, int n_in,
                              void* d_out, int out_size, void* d_ws, size_t ws_size,
                              hipStream_t stream) {
  const float* pred = (const float*)d_in[0];
  const float* args = (const float*)d_in[1];
  const float* U    = (const float*)d_in[2];
  const float* b1   = (const float*)d_in[3];
  const float* b2   = (const float*)d_in[4];
  float* out = (float*)d_out;

  const size_t PRED_ELEMS = (size_t)NTOK * HID;         // 2,097,152
  const size_t U_ELEMS    = (size_t)HID * ROLES * HID;  // 16,777,216
  const size_t WS_NEEDED  = (PRED_ELEMS + U_ELEMS) * sizeof(_Float16); // ~36 MiB

  if (ws_size < WS_NEEDED) {
    hipLaunchKernelGGL(fallback_k, dim3((NTOK * ROLES) / 256), dim3(256), 0, stream,
                       pred, args, U, b1, b2, out);
    return;
  }

  _Float16* predf = (_Float16*)d_ws;
  _Float16* utf   = predf + PRED_ELEMS;

  hipLaunchKernelGGL(cvt_pred, dim3((unsigned)(PRED_ELEMS / 4 / 256)), dim3(256), 0, stream,
                     pred, predf, out, b2);
  hipLaunchKernelGGL(cvt_u, dim3(HID / 128, HID / 128, ROLES), dim3(256), 0, stream,
                     U, utf);
  hipLaunchKernelGGL(bilinear_mfma, dim3(HID / BN, NTOK / BM, ROLES), dim3(256), 0, stream,
                     predf, utf, args, b1, out);
}

// Round 8
// 355.884 us; speedup vs baseline: 1.1398x; 1.1398x over previous
//
#include <hip/hip_runtime.h>
#include <stdint.h>

// BilinearScorer: out[n,r] = sum_{h,k} pred[n,h] U[h,r,k] args[n,k] + bias1[r,:].args[n,:] + bias2[r]
// n=4096, h=k=512, R=64.  137.4 GFLOP fp32-equivalent.
// R8 = R5's verified geometry (16x16x32, BM/BN=128, BK=32, R2 swizzle: 0 conflicts
// across R2/R5/R6) + ping-pong double-buffered staging: ONE barrier per round, and
// each round's loads are issued a full compute-phase before their drain -> the
// vmcnt(0)-at-barrier cost (R5's limiter: MfmaUtil 26% == MFMA-work/wall) vanishes.
// R7 lesson: 32x32 reader pattern bank-conflicts (1.7e7); 16x16 pattern is the
// HW-verified conflict-free one.  fp16 single-pass numerics (absmax 0.25 passes).

#define HID   512
#define ROLES 64
#define NTOK  4096
#define BM    128
#define BN    128
#define BK    32

typedef __attribute__((ext_vector_type(8))) _Float16 f16x8;  // MFMA A/B operand: 4 VGPRs
typedef __attribute__((ext_vector_type(4))) _Float16 f16x4;
typedef __attribute__((ext_vector_type(4))) float    f32x4;

__device__ __forceinline__ void async16(const void* g, void* l) {
  // global -> LDS direct copy, 16B/lane. LDS dest is wave-uniform base + lane*16;
  // per-lane SOURCE address is free (implements the store-side swizzle).
  __builtin_amdgcn_global_load_lds(
      (const __attribute__((address_space(1))) uint32_t*)g,
      (__attribute__((address_space(3))) uint32_t*)l, 16, 0, 0);
}

// ---- prep: pred fp32 -> fp16, fused out[n,r] = bias2[r] init (R5-identical) ----
__global__ __launch_bounds__(256) void cvt_pred(const float* __restrict__ in,
                                                _Float16* __restrict__ outp,
                                                float* __restrict__ o,
                                                const float* __restrict__ b2) {
  const int idx = blockIdx.x * 256 + threadIdx.x;        // NTOK*HID/4 = 524288 threads
  const float4 v = ((const float4*)in)[idx];
  f16x4 t;
  t[0] = (_Float16)v.x; t[1] = (_Float16)v.y;
  t[2] = (_Float16)v.z; t[3] = (_Float16)v.w;
  ((f16x4*)outp)[idx] = t;
  if (idx < NTOK * ROLES) o[idx] = b2[idx & (ROLES - 1)];  // 262144 < 524288
}

// ---- prep: U[h][r][k] -> Ut[r][k][h] fp16, 128x128 fp32 LDS tile (R5-identical) ----
__global__ __launch_bounds__(256) void cvt_u(const float* __restrict__ U,
                                             _Float16* __restrict__ ut) {
  __shared__ float tile[128][129];               // stride 129 words: col reads conflict-free
  const int h0 = blockIdx.x * 128, k0 = blockIdx.y * 128, r = blockIdx.z;
  const int t = threadIdx.x;
  // read: 16 passes x 8 rows; 512B contiguous per row
  const int rr = t >> 5, c4 = (t & 31) * 4;
#pragma unroll
  for (int pass = 0; pass < 16; pass++) {
    const int row = pass * 8 + rr;
    const float4 v = *(const float4*)(U + ((size_t)(h0 + row) * ROLES + r) * HID + k0 + c4);
    tile[row][c4 + 0] = v.x; tile[row][c4 + 1] = v.y;
    tile[row][c4 + 2] = v.z; tile[row][c4 + 3] = v.w;
  }
  __syncthreads();
  // write: 8 passes x 16 k-rows; 256B contiguous per k-row
  const int kr = t >> 4, hc = (t & 15) * 8;
#pragma unroll
  for (int pass = 0; pass < 8; pass++) {
    const int k = pass * 16 + kr;
    alignas(16) _Float16 hb[8];
#pragma unroll
    for (int j = 0; j < 8; j++) hb[j] = (_Float16)tile[hc + j][k];
    *(uint4*)(ut + ((size_t)r * HID + k0 + k) * HID + h0 + hc) = *(const uint4*)hb;
  }
}

// ---- main fused GEMM, double-buffered ------------------------------------
__global__ __launch_bounds__(256, 3) void bilinear_mfma(
    const _Float16* __restrict__ predf, const _Float16* __restrict__ utf,
    const float* __restrict__ args, const float* __restrict__ bias1,
    float* __restrict__ out) {
  __shared__ _Float16 sA0[BM * BK];              // 8 KB each, 32 KB total
  __shared__ _Float16 sA1[BM * BK];
  __shared__ _Float16 sB0[BN * BK];
  __shared__ _Float16 sB1[BN * BK];

  const int nblk = blockIdx.x, mblk = blockIdx.y, r = blockIdx.z;
  const int m0 = mblk * BM, n0 = nblk * BN;
  const int tid  = threadIdx.x;
  const int wave = tid >> 6, lane = tid & 63;
  const int col  = lane & 15, quad = lane >> 4;
  const int wm = (wave & 1) * 64, wn = (wave >> 1) * 64;

  // staging (R2-verified): tile = 128 rows x 32 f16 (64B/row) = 512 x 16B chunks.
  // Thread tid writes chunk tid (rows 0..63) and chunk 256+tid (rows 64..127).
  // XOR swizzle: LDS slot jl of row i holds global chunk (jl ^ ((i>>1)&3)).
  const int i0  = tid >> 2;                      // row 0..63
  const int sw  = (i0 >> 1) & 3;                 // same for row i0+64
  const int ko  = ((tid & 3) ^ sw) * 8;          // swizzled source k-chunk
  const size_t offA0 = (size_t)(m0 + i0) * HID + ko;
  const size_t offA1 = offA0 + (size_t)64 * HID;
  const size_t offB0 = ((size_t)r * HID + n0 + i0) * HID + ko;
  const size_t offB1 = offB0 + (size_t)64 * HID;
  const int ldsOff0 = wave * 512;                // f16 elems; wave-uniform base
  const int ldsOff1 = 2048 + wave * 512;

  // reader slot (R2-verified conflict-free): row = .. + col; (row>>1)&3 == (col>>1)&3
  const int slot8 = (quad ^ ((col >> 1) & 3)) * 8;
  int rowA[4], rowB[4];
#pragma unroll
  for (int mt = 0; mt < 4; mt++) rowA[mt] = (wm + mt * 16 + col) * BK;
#pragma unroll
  for (int nt = 0; nt < 4; nt++) rowB[nt] = (wn + nt * 16 + col) * BK;

  f32x4 acc[4][4];
#pragma unroll
  for (int a = 0; a < 4; a++)
#pragma unroll
    for (int b = 0; b < 4; b++) acc[a][b] = (f32x4){0.f, 0.f, 0.f, 0.f};

  auto stage = [&](int kk, _Float16* dA, _Float16* dB) {
    async16(predf + offA0 + kk, dA + ldsOff0);
    async16(predf + offA1 + kk, dA + ldsOff1);
    async16(utf   + offB0 + kk, dB + ldsOff0);
    async16(utf   + offB1 + kk, dB + ldsOff1);
  };
  auto compute = [&](const _Float16* cA, const _Float16* cB) {
    f16x8 a[4], b[4];
#pragma unroll
    for (int mt = 0; mt < 4; mt++) a[mt] = *(const f16x8*)(cA + rowA[mt] + slot8);
#pragma unroll
    for (int nt = 0; nt < 4; nt++) b[nt] = *(const f16x8*)(cB + rowB[nt] + slot8);
#pragma unroll
    for (int mt = 0; mt < 4; mt++)
#pragma unroll
      for (int nt = 0; nt < 4; nt++)
        acc[mt][nt] = __builtin_amdgcn_mfma_f32_16x16x32_f16(a[mt], b[nt], acc[mt][nt], 0, 0, 0);
  };

  // ping-pong: one barrier per round; each round's loads drain a full compute later.
  stage(0, sA0, sB0);
#pragma unroll
  for (int t = 0; t < 16; t += 2) {
    __syncthreads();                             // tile t ready; buf1 free to overwrite
    if (t + 1 < 16) stage((t + 1) * BK, sA1, sB1);
    compute(sA0, sB0);
    __syncthreads();                             // tile t+1 ready; buf0 free to overwrite
    if (t + 2 < 16) stage((t + 2) * BK, sA0, sB0);
    compute(sA1, sB1);
  }

  // epilogue (R5-identical): partial[m] = sum_n (T[m,n]+bias1[r,n])*args[m,n]
  float b1v[4];
#pragma unroll
  for (int nt = 0; nt < 4; nt++)
    b1v[nt] = bias1[r * HID + n0 + wn + nt * 16 + col];

#pragma unroll
  for (int mt = 0; mt < 4; mt++) {
#pragma unroll
    for (int reg = 0; reg < 4; reg++) {
      const int m = m0 + wm + mt * 16 + quad * 4 + reg;   // C/D row = quad*4+reg (m89)
      const float* arow = args + (size_t)m * HID + n0 + wn + col;
      float s = 0.f;
#pragma unroll
      for (int nt = 0; nt < 4; nt++)
        s += (acc[mt][nt][reg] + b1v[nt]) * arow[nt * 16];
      s += __shfl_xor(s, 1);
      s += __shfl_xor(s, 2);
      s += __shfl_xor(s, 4);
      s += __shfl_xor(s, 8);                     // reduce 16-lane col group
      if (col == 0) atomicAdd(out + (size_t)m * ROLES + r, s);
    }
  }
}

// ---- correctness fallback if workspace is too small (slow, pure fp32) -----
__global__ __launch_bounds__(256) void fallback_k(
    const float* __restrict__ pred, const float* __restrict__ args,
    const float* __restrict__ U, const float* __restrict__ b1,
    const float* __restrict__ b2, float* __restrict__ out) {
  const int idx = blockIdx.x * 256 + threadIdx.x;   // 262144
  const int r = idx >> 12;                          // block-uniform role
  const int n = idx & (NTOK - 1);
  const float* arow = args + (size_t)n * HID;
  const float* prow = pred + (size_t)n * HID;
  float acc = 0.f;
  for (int h = 0; h < HID; h++) {
    const float* urow = U + ((size_t)h * ROLES + r) * HID;
    float s = 0.f;
    for (int k = 0; k < HID; k++) s = fmaf(urow[k], arow[k], s);
    acc = fmaf(prow[h], s, acc);
  }
  float sb = 0.f;
  const float* brow = b1 + (size_t)r * HID;
  for (int k = 0; k < HID; k++) sb = fmaf(brow[k], arow[k], sb);
  out[(size_t)n * ROLES + r] = acc + sb + b2[r];
}

extern "C" void kernel_launch(void* const* d_in, const int* in_sizes, int n_in,
                              void* d_out, int out_size, void* d_ws, size_t ws_size,
                              hipStream_t stream) {
  const float* pred = (const float*)d_in[0];
  const float* args = (const float*)d_in[1];
  const float* U    = (const float*)d_in[2];
  const float* b1   = (const float*)d_in[3];
  const float* b2   = (const float*)d_in[4];
  float* out = (float*)d_out;

  const size_t PRED_ELEMS = (size_t)NTOK * HID;         // 2,097,152
  const size_t U_ELEMS    = (size_t)HID * ROLES * HID;  // 16,777,216
  const size_t WS_NEEDED  = (PRED_ELEMS + U_ELEMS) * sizeof(_Float16); // ~36 MiB

  if (ws_size < WS_NEEDED) {
    hipLaunchKernelGGL(fallback_k, dim3((NTOK * ROLES) / 256), dim3(256), 0, stream,
                       pred, args, U, b1, b2, out);
    return;
  }

  _Float16* predf = (_Float16*)d_ws;
  _Float16* utf   = predf + PRED_ELEMS;

  hipLaunchKernelGGL(cvt_pred, dim3((unsigned)(PRED_ELEMS / 4 / 256)), dim3(256), 0, stream,
                     pred, predf, out, b2);
  hipLaunchKernelGGL(cvt_u, dim3(HID / 128, HID / 128, ROLES), dim3(256), 0, stream,
                     U, utf);
  hipLaunchKernelGGL(bilinear_mfma, dim3(HID / BN, NTOK / BM, ROLES), dim3(256), 0, stream,
                     predf, utf, args, b1, out);
}